// Round 1
// baseline (102.100 us; speedup 1.0000x reference)
//
#include <hip/hip_runtime.h>

// Problem dims (fixed by reference)
#define BB 4
#define LL 1024
#define DD 64
#define UU 32

// ---------------------------------------------------------------------------
// K1: precompute Eq[b,l,u] = exp(2*(inputs@Wt + bh)), Ek[b,l,u] = exp(2*(inputs@Wx))
// so that tanh(q+k+bh) = 1 - 2/(1 + Eq*Ek). 131K exps instead of 134M tanh.
// ---------------------------------------------------------------------------
__global__ __launch_bounds__(256) void precompute_kernel(
    const float* __restrict__ inp, const float* __restrict__ Wt,
    const float* __restrict__ Wx, const float* __restrict__ bh,
    float* __restrict__ Eq, float* __restrict__ Ek)
{
    __shared__ float s_in[8][DD];   // 8 rows staged per block
    int t = threadIdx.x;
    int row0 = blockIdx.x * 8;
    if (t < 128) {
        ((float4*)s_in)[t] = ((const float4*)(inp + (size_t)row0 * DD))[t];
    }
    __syncthreads();
    int r = t >> 5;      // 0..7 row within block
    int u = t & 31;      // 0..31
    size_t row = row0 + r;
    float q = 0.f, k = 0.f;
#pragma unroll
    for (int d = 0; d < DD; ++d) {
        float x = s_in[r][d];
        q = fmaf(x, Wt[d * UU + u], q);
        k = fmaf(x, Wx[d * UU + u], k);
    }
    float eq = expf(2.f * (q + bh[u]));
    float ek = expf(2.f * k);
    Eq[row * UU + u] = eq;
    Ek[row * UU + u] = ek;
}

// ---------------------------------------------------------------------------
// Block-wide reductions (256 threads = 4 waves)
// ---------------------------------------------------------------------------
__device__ __forceinline__ float block_reduce_max(float v, float* sred, int t) {
#pragma unroll
    for (int m = 32; m >= 1; m >>= 1) v = fmaxf(v, __shfl_xor(v, m, 64));
    __syncthreads();                      // protect sred reuse
    if ((t & 63) == 0) sred[t >> 6] = v;
    __syncthreads();
    return fmaxf(fmaxf(sred[0], sred[1]), fmaxf(sred[2], sred[3]));
}
__device__ __forceinline__ float block_reduce_sum(float v, float* sred, int t) {
#pragma unroll
    for (int m = 32; m >= 1; m >>= 1) v += __shfl_xor(v, m, 64);
    __syncthreads();
    if ((t & 63) == 0) sred[t >> 6] = v;
    __syncthreads();
    return (sred[0] + sred[1]) + (sred[2] + sred[3]);
}

// ---------------------------------------------------------------------------
// K2: fused e -> softmax -> v for TI=4 query rows per block.
// grid = B*L/4 = 1024 blocks, 256 threads.
//   Phase A: thread t owns j = jj*256+t (4 j's). e_ij = -2 * sum_u Wa_u * rcp(1+Eq_iu*Ek_ju)
//            (constant terms ba + sum(Wa) cancel in softmax)
//   Softmax per row i via block reductions; a stored to LDS as s_a[j][i] (float4able).
//   Phase B: thread = (dq=t&15, g=t>>4); j = jj*16+g; 16 fma per j on float4 of inputs.
// ---------------------------------------------------------------------------
__global__ __launch_bounds__(256) void attn_kernel(
    const float* __restrict__ Eq, const float* __restrict__ Ek,
    const float* __restrict__ inp, const float* __restrict__ Wa,
    float* __restrict__ out)
{
    __shared__ float  s_a[LL][4];          // 16 KB: a[j][i]
    __shared__ float4 s_v[16][4][16];      // 16 KB: partials [g][i][dq]
    __shared__ float  s_red[4];

    int t  = threadIdx.x;
    int b  = blockIdx.x >> 8;
    int i0 = (blockIdx.x & 255) * 4;

    const float* ekb = Ek + (size_t)b * LL * UU;

    // ---------------- Phase A: scores ----------------
    float e[4][4];   // [i][jj]
#pragma unroll
    for (int jj = 0; jj < 4; ++jj) {
        int j = jj * 256 + t;
        const float4* ekp = (const float4*)(ekb + (size_t)j * UU);
        float4 ekv[8];
#pragma unroll
        for (int u4 = 0; u4 < 8; ++u4) ekv[u4] = ekp[u4];
#pragma unroll
        for (int i = 0; i < 4; ++i) {
            const float* eqr = Eq + ((size_t)(b * LL + i0 + i)) * UU;  // wave-uniform
            float acc = 0.f;
#pragma unroll
            for (int u4 = 0; u4 < 8; ++u4) {
                const float* eqq = eqr + u4 * 4;
                const float* waq = Wa + u4 * 4;
                acc = fmaf(waq[0], __builtin_amdgcn_rcpf(fmaf(eqq[0], ekv[u4].x, 1.f)), acc);
                acc = fmaf(waq[1], __builtin_amdgcn_rcpf(fmaf(eqq[1], ekv[u4].y, 1.f)), acc);
                acc = fmaf(waq[2], __builtin_amdgcn_rcpf(fmaf(eqq[2], ekv[u4].z, 1.f)), acc);
                acc = fmaf(waq[3], __builtin_amdgcn_rcpf(fmaf(eqq[3], ekv[u4].w, 1.f)), acc);
            }
            e[i][jj] = -2.f * acc;
        }
    }

    // ---------------- Softmax per row ----------------
    float rs[4];
#pragma unroll
    for (int i = 0; i < 4; ++i) {
        float tm = fmaxf(fmaxf(e[i][0], e[i][1]), fmaxf(e[i][2], e[i][3]));
        float m = block_reduce_max(tm, s_red, t);
        float s = 0.f;
#pragma unroll
        for (int jj = 0; jj < 4; ++jj) {
            e[i][jj] = __expf(e[i][jj] - m);
            s += e[i][jj];
        }
        s = block_reduce_sum(s, s_red, t);
        rs[i] = 1.0f / (s + 1e-8f);        // reference's +1e-8 denominator
    }
#pragma unroll
    for (int jj = 0; jj < 4; ++jj) {
        float4 av;
        av.x = e[0][jj] * rs[0];
        av.y = e[1][jj] * rs[1];
        av.z = e[2][jj] * rs[2];
        av.w = e[3][jj] * rs[3];
        ((float4*)s_a)[jj * 256 + t] = av;
    }
    __syncthreads();

    // ---------------- Phase B: v = a @ inputs ----------------
    int dq = t & 15;    // d-quad: d = 4*dq .. 4*dq+3
    int g  = t >> 4;    // j-group 0..15 (interleaved j = jj*16+g)
    const float4* inp4 = (const float4*)(inp + (size_t)b * LL * DD);
    float4 v0 = {0,0,0,0}, v1 = {0,0,0,0}, v2 = {0,0,0,0}, v3 = {0,0,0,0};
#pragma unroll 4
    for (int jj = 0; jj < 64; ++jj) {
        int j = jj * 16 + g;
        float4 x  = inp4[j * 16 + dq];
        const float* ap = &s_a[j][0];
        float a0 = ap[0], a1 = ap[1], a2 = ap[2], a3 = ap[3];
        v0.x = fmaf(a0, x.x, v0.x); v0.y = fmaf(a0, x.y, v0.y);
        v0.z = fmaf(a0, x.z, v0.z); v0.w = fmaf(a0, x.w, v0.w);
        v1.x = fmaf(a1, x.x, v1.x); v1.y = fmaf(a1, x.y, v1.y);
        v1.z = fmaf(a1, x.z, v1.z); v1.w = fmaf(a1, x.w, v1.w);
        v2.x = fmaf(a2, x.x, v2.x); v2.y = fmaf(a2, x.y, v2.y);
        v2.z = fmaf(a2, x.z, v2.z); v2.w = fmaf(a2, x.w, v2.w);
        v3.x = fmaf(a3, x.x, v3.x); v3.y = fmaf(a3, x.y, v3.y);
        v3.z = fmaf(a3, x.z, v3.z); v3.w = fmaf(a3, x.w, v3.w);
    }
    s_v[g][0][dq] = v0;
    s_v[g][1][dq] = v1;
    s_v[g][2][dq] = v2;
    s_v[g][3][dq] = v3;
    __syncthreads();

    // final cross-group reduce + coalesced store
    int i = t >> 6;       // 0..3
    int d = t & 63;       // 0..63
    const float* svf = (const float*)s_v;
    float r = 0.f;
#pragma unroll
    for (int g2 = 0; g2 < 16; ++g2) r += svf[g2 * 256 + i * 64 + d];
    out[((size_t)b * LL + (i0 + i)) * DD + d] = r;
}

// ---------------------------------------------------------------------------
extern "C" void kernel_launch(void* const* d_in, const int* in_sizes, int n_in,
                              void* d_out, int out_size, void* d_ws, size_t ws_size,
                              hipStream_t stream) {
    const float* inp = (const float*)d_in[0];
    const float* Wt  = (const float*)d_in[1];
    const float* Wx  = (const float*)d_in[2];
    const float* Wa  = (const float*)d_in[3];
    const float* bh  = (const float*)d_in[4];
    // d_in[5] = ba (cancels in softmax), d_in[6] = attention_width (dead code)
    float* out = (float*)d_out;

    float* Eq = (float*)d_ws;                       // B*L*U floats = 512 KB
    float* Ek = Eq + (size_t)BB * LL * UU;          // another 512 KB

    precompute_kernel<<<BB * LL / 8, 256, 0, stream>>>(inp, Wt, Wx, bh, Eq, Ek);
    attn_kernel<<<BB * LL / 4, 256, 0, stream>>>(Eq, Ek, inp, Wa, out);
}

// Round 2
// 100.850 us; speedup vs baseline: 1.0124x; 1.0124x over previous
//
#include <hip/hip_runtime.h>

// Problem dims (fixed by reference)
#define BB 4
#define LL 1024
#define DD 64
#define UU 32
#define TI 4   // query rows per block

// ---------------------------------------------------------------------------
// K1: Eq[b,l,u] = exp(2*(inp@Wt + bh)), Ek[b,l,u] = exp(2*(inp@Wx))
// tanh(q+k+bh) = 1 - 2/(1 + Eq*Ek)
// ---------------------------------------------------------------------------
__global__ __launch_bounds__(256) void precompute_kernel(
    const float* __restrict__ inp, const float* __restrict__ Wt,
    const float* __restrict__ Wx, const float* __restrict__ bh,
    float* __restrict__ Eq, float* __restrict__ Ek)
{
    __shared__ float s_in[8][DD];       // 2 KB
    __shared__ float s_wt[DD][UU];      // 8 KB
    __shared__ float s_wx[DD][UU];      // 8 KB
    int t = threadIdx.x;
    int row0 = blockIdx.x * 8;
    if (t < 128)
        ((float4*)s_in)[t] = ((const float4*)(inp + (size_t)row0 * DD))[t];
#pragma unroll
    for (int p = 0; p < 2; ++p) {
        ((float4*)s_wt)[p * 256 + t] = ((const float4*)Wt)[p * 256 + t];
        ((float4*)s_wx)[p * 256 + t] = ((const float4*)Wx)[p * 256 + t];
    }
    __syncthreads();
    int r = t >> 5;      // row within block
    int u = t & 31;
    size_t row = row0 + r;
    float q = 0.f, k = 0.f;
#pragma unroll
    for (int d = 0; d < DD; ++d) {
        float x = s_in[r][d];                 // broadcast within half-wave
        q = fmaf(x, s_wt[d][u], q);           // bank = u: conflict-free
        k = fmaf(x, s_wx[d][u], k);
    }
    Eq[row * UU + u] = __expf(2.f * (q + bh[u]));
    Ek[row * UU + u] = __expf(2.f * k);
}

// ---------------------------------------------------------------------------
// K2: fused scores -> softmax -> v for TI=4 query rows per block.
// grid = B*L/TI = 1024 blocks, 256 threads (4 waves).
// Phase A (quad-rcp): for u-quad (u0..u3) with p_u = 1 + Eq_iu*Ek_ju:
//   sum_u wa_u/p_u = [ (wa0*q+wa1*p)*rs + (wa2*s+wa3*r)*pq ] / (pq*rs)
//   -> 13 fma/mul + 1 v_rcp per 4 elements (vs 8 fma + 4 rcp).
//   e_ij = -2 * acc (constant terms ba + sum(Wa) cancel in softmax).
// ---------------------------------------------------------------------------
union ShMem {
    float  a[LL][TI];         // 16 KB: softmax weights a[j][i]
    float4 v[16][TI][16];     // 16 KB: phase-B partials [g][i][dq] (after barrier)
};

__global__ __launch_bounds__(256) void attn_kernel(
    const float* __restrict__ Eq, const float* __restrict__ Ek,
    const float* __restrict__ inp, const float* __restrict__ Wa,
    float* __restrict__ out)
{
    __shared__ ShMem sh;
    __shared__ float s_red[8][TI];

    int t  = threadIdx.x;
    int w  = t >> 6;                    // wave id 0..3
    int b  = blockIdx.x >> 8;
    int i0 = (blockIdx.x & 255) * TI;

    const float4* ekb4 = (const float4*)(Ek + (size_t)b * LL * UU);
    const float*  eqb  = Eq + ((size_t)(b * LL + i0)) * UU;   // block-uniform

    // ---------------- Phase A: scores (u4-outer, double-buffered Ek) --------
    float acc[TI][4];
#pragma unroll
    for (int i = 0; i < TI; ++i)
#pragma unroll
        for (int jj = 0; jj < 4; ++jj) acc[i][jj] = 0.f;

    const float4* ekp[4];
#pragma unroll
    for (int jj = 0; jj < 4; ++jj) ekp[jj] = ekb4 + (size_t)(jj * 256 + t) * 8;

    float4 cur[4], nxt[4];
#pragma unroll
    for (int jj = 0; jj < 4; ++jj) cur[jj] = ekp[jj][0];

#pragma unroll
    for (int u4 = 0; u4 < 8; ++u4) {
        if (u4 < 7) {
#pragma unroll
            for (int jj = 0; jj < 4; ++jj) nxt[jj] = ekp[jj][u4 + 1];
        }
#pragma unroll
        for (int i = 0; i < TI; ++i) {
            const float* eqq = eqb + i * UU + u4 * 4;   // s_load_dwordx4
            float eq0 = eqq[0], eq1 = eqq[1], eq2 = eqq[2], eq3 = eqq[3];
            const float* waq = Wa + u4 * 4;             // s_load_dwordx4
            float wa0 = waq[0], wa1 = waq[1], wa2 = waq[2], wa3 = waq[3];
#pragma unroll
            for (int jj = 0; jj < 4; ++jj) {
                float4 ek = cur[jj];
                float p  = fmaf(eq0, ek.x, 1.f);
                float q  = fmaf(eq1, ek.y, 1.f);
                float r  = fmaf(eq2, ek.z, 1.f);
                float s  = fmaf(eq3, ek.w, 1.f);
                float n01 = fmaf(wa0, q, wa1 * p);
                float n23 = fmaf(wa2, s, wa3 * r);
                float pq = p * q, rs = r * s;
                float num = fmaf(n01, rs, n23 * pq);
                float den = pq * rs;                    // <= ~2e23, no overflow
                acc[i][jj] = fmaf(num, __builtin_amdgcn_rcpf(den), acc[i][jj]);
            }
        }
        if (u4 < 7) {
#pragma unroll
            for (int jj = 0; jj < 4; ++jj) cur[jj] = nxt[jj];
        }
    }

    float ev[TI][4];
#pragma unroll
    for (int i = 0; i < TI; ++i)
#pragma unroll
        for (int jj = 0; jj < 4; ++jj) ev[i][jj] = -2.f * acc[i][jj];

    // ---------------- Softmax: wave-reduce all rows, then 2 barriers --------
    float wred[TI];
#pragma unroll
    for (int i = 0; i < TI; ++i) {
        float v = fmaxf(fmaxf(ev[i][0], ev[i][1]), fmaxf(ev[i][2], ev[i][3]));
#pragma unroll
        for (int m = 32; m >= 1; m >>= 1) v = fmaxf(v, __shfl_xor(v, m, 64));
        wred[i] = v;
    }
    if ((t & 63) == 0) {
#pragma unroll
        for (int i = 0; i < TI; ++i) s_red[w][i] = wred[i];
    }
    __syncthreads();                                             // B1
    float m[TI];
#pragma unroll
    for (int i = 0; i < TI; ++i)
        m[i] = fmaxf(fmaxf(s_red[0][i], s_red[1][i]),
                     fmaxf(s_red[2][i], s_red[3][i]));

#pragma unroll
    for (int i = 0; i < TI; ++i) {
        float s = 0.f;
#pragma unroll
        for (int jj = 0; jj < 4; ++jj) {
            ev[i][jj] = __expf(ev[i][jj] - m[i]);
            s += ev[i][jj];
        }
#pragma unroll
        for (int mm = 32; mm >= 1; mm >>= 1) s += __shfl_xor(s, mm, 64);
        wred[i] = s;
    }
    if ((t & 63) == 0) {
#pragma unroll
        for (int i = 0; i < TI; ++i) s_red[4 + w][i] = wred[i];
    }
    __syncthreads();                                             // B2
    float rs[TI];
#pragma unroll
    for (int i = 0; i < TI; ++i) {
        float s = ((s_red[4][i] + s_red[5][i]) + (s_red[6][i] + s_red[7][i]));
        rs[i] = 1.0f / (s + 1e-8f);          // reference's +1e-8 denominator
    }

#pragma unroll
    for (int jj = 0; jj < 4; ++jj) {
        float4 av;
        av.x = ev[0][jj] * rs[0];
        av.y = ev[1][jj] * rs[1];
        av.z = ev[2][jj] * rs[2];
        av.w = ev[3][jj] * rs[3];
        ((float4*)sh.a)[jj * 256 + t] = av;
    }
    __syncthreads();                                             // B3

    // ---------------- Phase B: v = a @ inputs ------------------------------
    int dq = t & 15;    // d-quad
    int g  = t >> 4;    // j-group 0..15
    const float4* inp4 = (const float4*)(inp + (size_t)b * LL * DD);
    float4 v0 = {0,0,0,0}, v1 = {0,0,0,0}, v2 = {0,0,0,0}, v3 = {0,0,0,0};
#pragma unroll 4
    for (int jj = 0; jj < 64; ++jj) {
        int j = jj * 16 + g;
        float4 x  = inp4[j * 16 + dq];
        float4 av = ((const float4*)sh.a)[j];     // ds_read_b128 broadcast
        v0.x = fmaf(av.x, x.x, v0.x); v0.y = fmaf(av.x, x.y, v0.y);
        v0.z = fmaf(av.x, x.z, v0.z); v0.w = fmaf(av.x, x.w, v0.w);
        v1.x = fmaf(av.y, x.x, v1.x); v1.y = fmaf(av.y, x.y, v1.y);
        v1.z = fmaf(av.y, x.z, v1.z); v1.w = fmaf(av.y, x.w, v1.w);
        v2.x = fmaf(av.z, x.x, v2.x); v2.y = fmaf(av.z, x.y, v2.y);
        v2.z = fmaf(av.z, x.z, v2.z); v2.w = fmaf(av.z, x.w, v2.w);
        v3.x = fmaf(av.w, x.x, v3.x); v3.y = fmaf(av.w, x.y, v3.y);
        v3.z = fmaf(av.w, x.z, v3.z); v3.w = fmaf(av.w, x.w, v3.w);
    }
    __syncthreads();                                             // B4 (a done)
    sh.v[g][0][dq] = v0;
    sh.v[g][1][dq] = v1;
    sh.v[g][2][dq] = v2;
    sh.v[g][3][dq] = v3;
    __syncthreads();                                             // B5

    int i = t >> 6;       // 0..3
    int d = t & 63;       // 0..63
    const float* svf = (const float*)sh.v;
    float r = 0.f;
#pragma unroll
    for (int g2 = 0; g2 < 16; ++g2) r += svf[g2 * 256 + i * 64 + d];
    out[((size_t)b * LL + (i0 + i)) * DD + d] = r;
}

// ---------------------------------------------------------------------------
extern "C" void kernel_launch(void* const* d_in, const int* in_sizes, int n_in,
                              void* d_out, int out_size, void* d_ws, size_t ws_size,
                              hipStream_t stream) {
    const float* inp = (const float*)d_in[0];
    const float* Wt  = (const float*)d_in[1];
    const float* Wx  = (const float*)d_in[2];
    const float* Wa  = (const float*)d_in[3];
    const float* bh  = (const float*)d_in[4];
    // d_in[5] = ba (cancels in softmax), d_in[6] = attention_width (dead code)
    float* out = (float*)d_out;

    float* Eq = (float*)d_ws;                       // B*L*U floats = 512 KB
    float* Ek = Eq + (size_t)BB * LL * UU;          // another 512 KB

    precompute_kernel<<<BB * LL / 8, 256, 0, stream>>>(inp, Wt, Wx, bh, Eq, Ek);
    attn_kernel<<<BB * LL / TI, 256, 0, stream>>>(Eq, Ek, inp, Wa, out);
}

// Round 3
// 98.433 us; speedup vs baseline: 1.0373x; 1.0246x over previous
//
#include <hip/hip_runtime.h>

// Problem dims (fixed by reference)
#define BB 4
#define LL 1024
#define DD 64
#define UU 32
#define TI 8     // query rows per block
#define NT 512   // threads per block (8 waves)

// ---------------------------------------------------------------------------
// K1: Eq[b,l,u] = exp(2*(inp@Wt + bh)), Ek[b,l,u] = exp(2*(inp@Wx))
// tanh(q+k+bh) = 1 - 2/(1 + Eq*Ek)
// ---------------------------------------------------------------------------
__global__ __launch_bounds__(256) void precompute_kernel(
    const float* __restrict__ inp, const float* __restrict__ Wt,
    const float* __restrict__ Wx, const float* __restrict__ bh,
    float* __restrict__ Eq, float* __restrict__ Ek)
{
    __shared__ float s_in[8][DD];       // 2 KB
    __shared__ float s_wt[DD][UU];      // 8 KB
    __shared__ float s_wx[DD][UU];      // 8 KB
    int t = threadIdx.x;
    int row0 = blockIdx.x * 8;
    if (t < 128)
        ((float4*)s_in)[t] = ((const float4*)(inp + (size_t)row0 * DD))[t];
#pragma unroll
    for (int p = 0; p < 2; ++p) {
        ((float4*)s_wt)[p * 256 + t] = ((const float4*)Wt)[p * 256 + t];
        ((float4*)s_wx)[p * 256 + t] = ((const float4*)Wx)[p * 256 + t];
    }
    __syncthreads();
    int r = t >> 5;
    int u = t & 31;
    size_t row = row0 + r;
    float q = 0.f, k = 0.f;
#pragma unroll
    for (int d = 0; d < DD; ++d) {
        float x = s_in[r][d];
        q = fmaf(x, s_wt[d][u], q);
        k = fmaf(x, s_wx[d][u], k);
    }
    Eq[row * UU + u] = __expf(2.f * (q + bh[u]));
    Ek[row * UU + u] = __expf(2.f * k);
}

// ---------------------------------------------------------------------------
// K2: fused scores -> softmax -> v, TI=8 rows/block, 512 threads.
// grid = B*L/TI = 512 blocks (2/CU). Halves L2 traffic vs TI=4.
// Phase A quad-rcp: sum_u wa_u/p_u over a u-quad with one v_rcp.
// ---------------------------------------------------------------------------
union ShMem {
    struct { float a0[LL][4]; float a1[LL][4]; } a;   // 32 KB: a[j][i0..3], a[j][i4..7]
    float4 v[8][TI][16];                               // 16 KB: partials [wave][i][dq]
};

__global__ __launch_bounds__(NT) void attn_kernel(
    const float* __restrict__ Eq, const float* __restrict__ Ek,
    const float* __restrict__ inp, const float* __restrict__ Wa,
    float* __restrict__ out)
{
    __shared__ ShMem sh;
    __shared__ float s_red[2][8][TI];   // [stage][wave][row]

    int t  = threadIdx.x;
    int w  = t >> 6;                    // wave 0..7
    int b  = blockIdx.x >> 7;
    int i0 = (blockIdx.x & 127) * TI;

    const float4* ekb4 = (const float4*)(Ek + (size_t)b * LL * UU);
    const float*  eqb  = Eq + ((size_t)(b * LL + i0)) * UU;   // block-uniform

    // ---------------- Phase A: scores (u4-outer, double-buffered Ek) --------
    float acc[TI][2];
#pragma unroll
    for (int i = 0; i < TI; ++i) { acc[i][0] = 0.f; acc[i][1] = 0.f; }

    const float4* ekp0 = ekb4 + (size_t)t * 8;           // j = t
    const float4* ekp1 = ekb4 + (size_t)(NT + t) * 8;    // j = 512 + t
    float4 cur0 = ekp0[0], cur1 = ekp1[0];

#pragma unroll
    for (int u4 = 0; u4 < 8; ++u4) {
        float4 nxt0, nxt1;
        if (u4 < 7) { nxt0 = ekp0[u4 + 1]; nxt1 = ekp1[u4 + 1]; }
        const float* waq = Wa + u4 * 4;                  // s_load_dwordx4
        float wa0 = waq[0], wa1 = waq[1], wa2 = waq[2], wa3 = waq[3];
#pragma unroll
        for (int i = 0; i < TI; ++i) {
            const float* eqq = eqb + i * UU + u4 * 4;    // s_load_dwordx4
            float eq0 = eqq[0], eq1 = eqq[1], eq2 = eqq[2], eq3 = eqq[3];
#pragma unroll
            for (int jj = 0; jj < 2; ++jj) {
                float4 ek = jj ? cur1 : cur0;
                float p  = fmaf(eq0, ek.x, 1.f);
                float q  = fmaf(eq1, ek.y, 1.f);
                float r  = fmaf(eq2, ek.z, 1.f);
                float s  = fmaf(eq3, ek.w, 1.f);
                float n01 = fmaf(wa0, q, wa1 * p);
                float n23 = fmaf(wa2, s, wa3 * r);
                float pq = p * q, rs = r * s;
                float num = fmaf(n01, rs, n23 * pq);
                float den = pq * rs;                     // <= ~4e22, safe in fp32
                acc[i][jj] = fmaf(num, __builtin_amdgcn_rcpf(den), acc[i][jj]);
            }
        }
        if (u4 < 7) { cur0 = nxt0; cur1 = nxt1; }
    }

    float ev[TI][2];
#pragma unroll
    for (int i = 0; i < TI; ++i) {
        ev[i][0] = -2.f * acc[i][0];
        ev[i][1] = -2.f * acc[i][1];
    }

    // ---------------- Softmax: batched wave reductions, 2 barriers ----------
    float wred[TI];
#pragma unroll
    for (int i = 0; i < TI; ++i) {
        float v = fmaxf(ev[i][0], ev[i][1]);
#pragma unroll
        for (int m = 32; m >= 1; m >>= 1) v = fmaxf(v, __shfl_xor(v, m, 64));
        wred[i] = v;
    }
    if ((t & 63) == 0) {
#pragma unroll
        for (int i = 0; i < TI; ++i) s_red[0][w][i] = wred[i];
    }
    __syncthreads();                                             // B1
    float m[TI];
#pragma unroll
    for (int i = 0; i < TI; ++i) {
        float v = s_red[0][0][i];
#pragma unroll
        for (int w2 = 1; w2 < 8; ++w2) v = fmaxf(v, s_red[0][w2][i]);
        m[i] = v;
    }

#pragma unroll
    for (int i = 0; i < TI; ++i) {
        ev[i][0] = __expf(ev[i][0] - m[i]);
        ev[i][1] = __expf(ev[i][1] - m[i]);
        float s = ev[i][0] + ev[i][1];
#pragma unroll
        for (int mm = 32; mm >= 1; mm >>= 1) s += __shfl_xor(s, mm, 64);
        wred[i] = s;
    }
    if ((t & 63) == 0) {
#pragma unroll
        for (int i = 0; i < TI; ++i) s_red[1][w][i] = wred[i];
    }
    __syncthreads();                                             // B2
    float rs[TI];
#pragma unroll
    for (int i = 0; i < TI; ++i) {
        float s = 0.f;
#pragma unroll
        for (int w2 = 0; w2 < 8; ++w2) s += s_red[1][w2][i];
        rs[i] = 1.0f / (s + 1e-8f);          // reference's +1e-8 denominator
    }

#pragma unroll
    for (int jj = 0; jj < 2; ++jj) {
        int j = jj * NT + t;
        float4 lo, hi;
        lo.x = ev[0][jj] * rs[0]; lo.y = ev[1][jj] * rs[1];
        lo.z = ev[2][jj] * rs[2]; lo.w = ev[3][jj] * rs[3];
        hi.x = ev[4][jj] * rs[4]; hi.y = ev[5][jj] * rs[5];
        hi.z = ev[6][jj] * rs[6]; hi.w = ev[7][jj] * rs[7];
        *(float4*)(&sh.a.a0[j][0]) = lo;
        *(float4*)(&sh.a.a1[j][0]) = hi;
    }
    __syncthreads();                                             // B3

    // ---------------- Phase B: v = a @ inputs ------------------------------
    int dq = t & 15;        // d-quad
    int g  = t >> 4;        // j-group 0..31
    const float4* inp4 = (const float4*)(inp + (size_t)b * LL * DD);
    float4 v[TI];
#pragma unroll
    for (int i = 0; i < TI; ++i) v[i] = (float4){0.f, 0.f, 0.f, 0.f};

#pragma unroll 4
    for (int jj = 0; jj < 32; ++jj) {
        int j = jj * 32 + g;
        float4 x  = inp4[j * 16 + dq];
        float4 a0 = *(const float4*)(&sh.a.a0[j][0]);   // b128 broadcast
        float4 a1 = *(const float4*)(&sh.a.a1[j][0]);
        v[0].x = fmaf(a0.x, x.x, v[0].x); v[0].y = fmaf(a0.x, x.y, v[0].y);
        v[0].z = fmaf(a0.x, x.z, v[0].z); v[0].w = fmaf(a0.x, x.w, v[0].w);
        v[1].x = fmaf(a0.y, x.x, v[1].x); v[1].y = fmaf(a0.y, x.y, v[1].y);
        v[1].z = fmaf(a0.y, x.z, v[1].z); v[1].w = fmaf(a0.y, x.w, v[1].w);
        v[2].x = fmaf(a0.z, x.x, v[2].x); v[2].y = fmaf(a0.z, x.y, v[2].y);
        v[2].z = fmaf(a0.z, x.z, v[2].z); v[2].w = fmaf(a0.z, x.w, v[2].w);
        v[3].x = fmaf(a0.w, x.x, v[3].x); v[3].y = fmaf(a0.w, x.y, v[3].y);
        v[3].z = fmaf(a0.w, x.z, v[3].z); v[3].w = fmaf(a0.w, x.w, v[3].w);
        v[4].x = fmaf(a1.x, x.x, v[4].x); v[4].y = fmaf(a1.x, x.y, v[4].y);
        v[4].z = fmaf(a1.x, x.z, v[4].z); v[4].w = fmaf(a1.x, x.w, v[4].w);
        v[5].x = fmaf(a1.y, x.x, v[5].x); v[5].y = fmaf(a1.y, x.y, v[5].y);
        v[5].z = fmaf(a1.y, x.z, v[5].z); v[5].w = fmaf(a1.y, x.w, v[5].w);
        v[6].x = fmaf(a1.z, x.x, v[6].x); v[6].y = fmaf(a1.z, x.y, v[6].y);
        v[6].z = fmaf(a1.z, x.z, v[6].z); v[6].w = fmaf(a1.z, x.w, v[6].w);
        v[7].x = fmaf(a1.w, x.x, v[7].x); v[7].y = fmaf(a1.w, x.y, v[7].y);
        v[7].z = fmaf(a1.w, x.z, v[7].z); v[7].w = fmaf(a1.w, x.w, v[7].w);
    }

    // reduce 4 j-groups within each wave (lanes differ in bits 4,5 of t)
#pragma unroll
    for (int i = 0; i < TI; ++i) {
        v[i].x += __shfl_xor(v[i].x, 16, 64); v[i].y += __shfl_xor(v[i].y, 16, 64);
        v[i].z += __shfl_xor(v[i].z, 16, 64); v[i].w += __shfl_xor(v[i].w, 16, 64);
        v[i].x += __shfl_xor(v[i].x, 32, 64); v[i].y += __shfl_xor(v[i].y, 32, 64);
        v[i].z += __shfl_xor(v[i].z, 32, 64); v[i].w += __shfl_xor(v[i].w, 32, 64);
    }
    __syncthreads();                     // B4: all a-reads done before union reuse
    if ((t & 63) < 16) {
#pragma unroll
        for (int i = 0; i < TI; ++i) sh.v[w][i][dq] = v[i];
    }
    __syncthreads();                                             // B5

    // final cross-wave reduce + coalesced store (512 output elements)
    int i = t >> 6;       // 0..7
    int d = t & 63;       // 0..63
    const float* svf = (const float*)sh.v;
    float r = 0.f;
#pragma unroll
    for (int w2 = 0; w2 < 8; ++w2) r += svf[w2 * (TI * 64) + i * 64 + d];
    out[((size_t)b * LL + (i0 + i)) * DD + d] = r;
}

// ---------------------------------------------------------------------------
extern "C" void kernel_launch(void* const* d_in, const int* in_sizes, int n_in,
                              void* d_out, int out_size, void* d_ws, size_t ws_size,
                              hipStream_t stream) {
    const float* inp = (const float*)d_in[0];
    const float* Wt  = (const float*)d_in[1];
    const float* Wx  = (const float*)d_in[2];
    const float* Wa  = (const float*)d_in[3];
    const float* bh  = (const float*)d_in[4];
    // d_in[5] = ba (cancels in softmax), d_in[6] = attention_width (dead code)
    float* out = (float*)d_out;

    float* Eq = (float*)d_ws;                       // B*L*U floats = 512 KB
    float* Ek = Eq + (size_t)BB * LL * UU;          // another 512 KB

    precompute_kernel<<<BB * LL / 8, 256, 0, stream>>>(inp, Wt, Wx, bh, Eq, Ek);
    attn_kernel<<<BB * LL / TI, NT, 0, stream>>>(Eq, Ek, inp, Wa, out);
}

// Round 4
// 98.202 us; speedup vs baseline: 1.0397x; 1.0024x over previous
//
#include <hip/hip_runtime.h>

// Problem dims (fixed by reference)
#define BB 4
#define LL 1024
#define DD 64
#define UU 32
#define TI 8     // query rows per block
#define NT 512   // threads per block (8 waves)

// ---------------------------------------------------------------------------
// K1: Eq[b,l,u] = exp(2*(inp@Wt + bh))   (layout [row][u], scalar-loaded later)
//     Ekt[b,u4,j] = float4 of exp(2*(inp@Wx)) for u=4*u4..4*u4+3  (TRANSPOSED:
//     lane-consecutive j -> coalesced float4 loads in attn phase A)
// tanh(q+k+bh) = 1 - 2/(1 + Eq*Ek)
// ---------------------------------------------------------------------------
__global__ __launch_bounds__(256) void precompute_kernel(
    const float* __restrict__ inp, const float* __restrict__ Wt,
    const float* __restrict__ Wx, const float* __restrict__ bh,
    float* __restrict__ Eq, float* __restrict__ Ekt)
{
    __shared__ float s_in[8][DD];       // 2 KB
    __shared__ float s_wt[DD][UU];      // 8 KB
    __shared__ float s_wx[DD][UU];      // 8 KB
    __shared__ float s_ek[8][36];       // padded: conflict-free b128 reads
    int t = threadIdx.x;
    int row0 = blockIdx.x * 8;
    if (t < 128)
        ((float4*)s_in)[t] = ((const float4*)(inp + (size_t)row0 * DD))[t];
#pragma unroll
    for (int p = 0; p < 2; ++p) {
        ((float4*)s_wt)[p * 256 + t] = ((const float4*)Wt)[p * 256 + t];
        ((float4*)s_wx)[p * 256 + t] = ((const float4*)Wx)[p * 256 + t];
    }
    __syncthreads();
    int r = t >> 5;
    int u = t & 31;
    size_t row = row0 + r;
    float q = 0.f, k = 0.f;
#pragma unroll
    for (int d = 0; d < DD; ++d) {
        float x = s_in[r][d];
        q = fmaf(x, s_wt[d][u], q);
        k = fmaf(x, s_wx[d][u], k);
    }
    Eq[row * UU + u] = __expf(2.f * (q + bh[u]));
    s_ek[r][u] = __expf(2.f * k);
    __syncthreads();
    // transposed write: Ekt[(b*8 + u4)*LL + l] (float4 units)
    if (t < 64) {
        int u4 = t >> 3, r2 = t & 7;
        float4 v = *(const float4*)(&s_ek[r2][u4 * 4]);
        size_t gr = row0 + r2;
        size_t bb_ = gr >> 10, l = gr & 1023;
        ((float4*)Ekt)[(bb_ * 8 + u4) * LL + l] = v;
    }
}

// ---------------------------------------------------------------------------
// K2: fused scores -> softmax -> v, TI=8 rows/block, 512 threads.
// grid = B*L/TI = 512 blocks (2/CU).
// Phase A quad-rcp: sum_u wa_u/p_u over a u-quad with one v_rcp; Ek loads are
// now lane-coalesced via the [u4][j] transpose.
// ---------------------------------------------------------------------------
union ShMem {
    struct { float a0[LL][4]; float a1[LL][4]; } a;   // 32 KB: a[j][i0..3], a[j][i4..7]
    float4 v[8][TI][16];                               // 16 KB: partials [wave][i][dq]
};

__global__ __launch_bounds__(NT) void attn_kernel(
    const float* __restrict__ Eq, const float* __restrict__ Ekt,
    const float* __restrict__ inp, const float* __restrict__ Wa,
    float* __restrict__ out)
{
    __shared__ ShMem sh;
    __shared__ float s_red[2][8][TI];   // [stage][wave][row]

    int t  = threadIdx.x;
    int w  = t >> 6;                    // wave 0..7
    int b  = blockIdx.x >> 7;
    int i0 = (blockIdx.x & 127) * TI;

    const float4* ektb = (const float4*)Ekt + (size_t)b * 8 * LL;
    const float*  eqb  = Eq + ((size_t)(b * LL + i0)) * UU;   // block-uniform

    // ---------------- Phase A: scores (u4-outer, double-buffered Ek) --------
    float acc[TI][2];
#pragma unroll
    for (int i = 0; i < TI; ++i) { acc[i][0] = 0.f; acc[i][1] = 0.f; }

    // coalesced: lane-consecutive float4
    float4 cur0 = ektb[t], cur1 = ektb[NT + t];

#pragma unroll
    for (int u4 = 0; u4 < 8; ++u4) {
        float4 nxt0, nxt1;
        if (u4 < 7) {
            nxt0 = ektb[(u4 + 1) * LL + t];
            nxt1 = ektb[(u4 + 1) * LL + NT + t];
        }
        const float* waq = Wa + u4 * 4;                  // s_load_dwordx4
        float wa0 = waq[0], wa1 = waq[1], wa2 = waq[2], wa3 = waq[3];
#pragma unroll
        for (int i = 0; i < TI; ++i) {
            const float* eqq = eqb + i * UU + u4 * 4;    // s_load_dwordx4
            float eq0 = eqq[0], eq1 = eqq[1], eq2 = eqq[2], eq3 = eqq[3];
#pragma unroll
            for (int jj = 0; jj < 2; ++jj) {
                float4 ek = jj ? cur1 : cur0;
                float p  = fmaf(eq0, ek.x, 1.f);
                float q  = fmaf(eq1, ek.y, 1.f);
                float r  = fmaf(eq2, ek.z, 1.f);
                float s  = fmaf(eq3, ek.w, 1.f);
                float n01 = fmaf(wa0, q, wa1 * p);
                float n23 = fmaf(wa2, s, wa3 * r);
                float pq = p * q, rs = r * s;
                float num = fmaf(n01, rs, n23 * pq);
                float den = pq * rs;                     // <= ~4e22, safe in fp32
                acc[i][jj] = fmaf(num, __builtin_amdgcn_rcpf(den), acc[i][jj]);
            }
        }
        if (u4 < 7) { cur0 = nxt0; cur1 = nxt1; }
    }

    float ev[TI][2];
#pragma unroll
    for (int i = 0; i < TI; ++i) {
        ev[i][0] = -2.f * acc[i][0];
        ev[i][1] = -2.f * acc[i][1];
    }

    // ---------------- Softmax: batched wave reductions, 2 barriers ----------
    float wred[TI];
#pragma unroll
    for (int i = 0; i < TI; ++i) {
        float v = fmaxf(ev[i][0], ev[i][1]);
#pragma unroll
        for (int m = 32; m >= 1; m >>= 1) v = fmaxf(v, __shfl_xor(v, m, 64));
        wred[i] = v;
    }
    if ((t & 63) == 0) {
#pragma unroll
        for (int i = 0; i < TI; ++i) s_red[0][w][i] = wred[i];
    }
    __syncthreads();                                             // B1
    float m[TI];
#pragma unroll
    for (int i = 0; i < TI; ++i) {
        float v = s_red[0][0][i];
#pragma unroll
        for (int w2 = 1; w2 < 8; ++w2) v = fmaxf(v, s_red[0][w2][i]);
        m[i] = v;
    }

#pragma unroll
    for (int i = 0; i < TI; ++i) {
        ev[i][0] = __expf(ev[i][0] - m[i]);
        ev[i][1] = __expf(ev[i][1] - m[i]);
        float s = ev[i][0] + ev[i][1];
#pragma unroll
        for (int mm = 32; mm >= 1; mm >>= 1) s += __shfl_xor(s, mm, 64);
        wred[i] = s;
    }
    if ((t & 63) == 0) {
#pragma unroll
        for (int i = 0; i < TI; ++i) s_red[1][w][i] = wred[i];
    }
    __syncthreads();                                             // B2
    float rs[TI];
#pragma unroll
    for (int i = 0; i < TI; ++i) {
        float s = 0.f;
#pragma unroll
        for (int w2 = 0; w2 < 8; ++w2) s += s_red[1][w2][i];
        rs[i] = 1.0f / (s + 1e-8f);          // reference's +1e-8 denominator
    }

#pragma unroll
    for (int jj = 0; jj < 2; ++jj) {
        int j = jj * NT + t;
        float4 lo, hi;
        lo.x = ev[0][jj] * rs[0]; lo.y = ev[1][jj] * rs[1];
        lo.z = ev[2][jj] * rs[2]; lo.w = ev[3][jj] * rs[3];
        hi.x = ev[4][jj] * rs[4]; hi.y = ev[5][jj] * rs[5];
        hi.z = ev[6][jj] * rs[6]; hi.w = ev[7][jj] * rs[7];
        *(float4*)(&sh.a.a0[j][0]) = lo;
        *(float4*)(&sh.a.a1[j][0]) = hi;
    }
    __syncthreads();                                             // B3

    // ---------------- Phase B: v = a @ inputs ------------------------------
    int dq = t & 15;        // d-quad
    int g  = t >> 4;        // j-group 0..31
    const float4* inp4 = (const float4*)(inp + (size_t)b * LL * DD);
    float4 v[TI];
#pragma unroll
    for (int i = 0; i < TI; ++i) v[i] = (float4){0.f, 0.f, 0.f, 0.f};

#pragma unroll 4
    for (int jj = 0; jj < 32; ++jj) {
        int j = jj * 32 + g;
        float4 x  = inp4[j * 16 + dq];
        float4 a0 = *(const float4*)(&sh.a.a0[j][0]);   // b128 broadcast
        float4 a1 = *(const float4*)(&sh.a.a1[j][0]);
        v[0].x = fmaf(a0.x, x.x, v[0].x); v[0].y = fmaf(a0.x, x.y, v[0].y);
        v[0].z = fmaf(a0.x, x.z, v[0].z); v[0].w = fmaf(a0.x, x.w, v[0].w);
        v[1].x = fmaf(a0.y, x.x, v[1].x); v[1].y = fmaf(a0.y, x.y, v[1].y);
        v[1].z = fmaf(a0.y, x.z, v[1].z); v[1].w = fmaf(a0.y, x.w, v[1].w);
        v[2].x = fmaf(a0.z, x.x, v[2].x); v[2].y = fmaf(a0.z, x.y, v[2].y);
        v[2].z = fmaf(a0.z, x.z, v[2].z); v[2].w = fmaf(a0.z, x.w, v[2].w);
        v[3].x = fmaf(a0.w, x.x, v[3].x); v[3].y = fmaf(a0.w, x.y, v[3].y);
        v[3].z = fmaf(a0.w, x.z, v[3].z); v[3].w = fmaf(a0.w, x.w, v[3].w);
        v[4].x = fmaf(a1.x, x.x, v[4].x); v[4].y = fmaf(a1.x, x.y, v[4].y);
        v[4].z = fmaf(a1.x, x.z, v[4].z); v[4].w = fmaf(a1.x, x.w, v[4].w);
        v[5].x = fmaf(a1.y, x.x, v[5].x); v[5].y = fmaf(a1.y, x.y, v[5].y);
        v[5].z = fmaf(a1.y, x.z, v[5].z); v[5].w = fmaf(a1.y, x.w, v[5].w);
        v[6].x = fmaf(a1.z, x.x, v[6].x); v[6].y = fmaf(a1.z, x.y, v[6].y);
        v[6].z = fmaf(a1.z, x.z, v[6].z); v[6].w = fmaf(a1.z, x.w, v[6].w);
        v[7].x = fmaf(a1.w, x.x, v[7].x); v[7].y = fmaf(a1.w, x.y, v[7].y);
        v[7].z = fmaf(a1.w, x.z, v[7].z); v[7].w = fmaf(a1.w, x.w, v[7].w);
    }

    // reduce 4 j-groups within each wave (lanes differ in bits 4,5 of t)
#pragma unroll
    for (int i = 0; i < TI; ++i) {
        v[i].x += __shfl_xor(v[i].x, 16, 64); v[i].y += __shfl_xor(v[i].y, 16, 64);
        v[i].z += __shfl_xor(v[i].z, 16, 64); v[i].w += __shfl_xor(v[i].w, 16, 64);
        v[i].x += __shfl_xor(v[i].x, 32, 64); v[i].y += __shfl_xor(v[i].y, 32, 64);
        v[i].z += __shfl_xor(v[i].z, 32, 64); v[i].w += __shfl_xor(v[i].w, 32, 64);
    }
    __syncthreads();                     // B4: all a-reads done before union reuse
    if ((t & 63) < 16) {
#pragma unroll
        for (int i = 0; i < TI; ++i) sh.v[w][i][dq] = v[i];
    }
    __syncthreads();                                             // B5

    // final cross-wave reduce + coalesced store (512 output elements)
    int i = t >> 6;       // 0..7
    int d = t & 63;       // 0..63
    const float* svf = (const float*)sh.v;
    float r = 0.f;
#pragma unroll
    for (int w2 = 0; w2 < 8; ++w2) r += svf[w2 * (TI * 64) + i * 64 + d];
    out[((size_t)b * LL + (i0 + i)) * DD + d] = r;
}

// ---------------------------------------------------------------------------
extern "C" void kernel_launch(void* const* d_in, const int* in_sizes, int n_in,
                              void* d_out, int out_size, void* d_ws, size_t ws_size,
                              hipStream_t stream) {
    const float* inp = (const float*)d_in[0];
    const float* Wt  = (const float*)d_in[1];
    const float* Wx  = (const float*)d_in[2];
    const float* Wa  = (const float*)d_in[3];
    const float* bh  = (const float*)d_in[4];
    // d_in[5] = ba (cancels in softmax), d_in[6] = attention_width (dead code)
    float* out = (float*)d_out;

    float* Eq  = (float*)d_ws;                      // B*L*U floats = 512 KB
    float* Ekt = Eq + (size_t)BB * LL * UU;         // transposed Ek, 512 KB

    precompute_kernel<<<BB * LL / 8, 256, 0, stream>>>(inp, Wt, Wx, bh, Eq, Ekt);
    attn_kernel<<<BB * LL / TI, NT, 0, stream>>>(Eq, Ekt, inp, Wa, out);
}